// Round 10
// baseline (77.875 us; speedup 1.0000x reference)
//
#include <hip/hip_runtime.h>
#include <hip/hip_fp16.h>

#define DIN 256
#define DOUT 128
#define KNBR 32
#define MT 128        // 4 waves x 32 rows; grid 391
#define KC 64         // K-chunk: 32 rows x 64 fp32 = 8 KB per wave per buf

typedef __attribute__((ext_vector_type(4))) float f32x4;
typedef __attribute__((ext_vector_type(8))) short bf16x8;

static __device__ __forceinline__ ushort f2bf(float f) {
    uint u = __float_as_uint(f);
    return (ushort)((u + 0x7FFFu + ((u >> 16) & 1u)) >> 16);   // RNE
}

// packed f32x2 -> bf16x2 (RNE); no builtin on gfx950 -> inline asm
static __device__ __forceinline__ uint cvtpk(float lo, float hi) {
    uint r;
    asm("v_cvt_pk_bf16_f32 %0, %1, %2" : "=v"(r) : "v"(lo), "v"(hi));
    return r;
}

// async global->LDS DMA, 16 B/lane, LDS dest = wave-uniform base + lane*16
static __device__ __forceinline__ void gload_lds16(const float* g, void* l) {
    __builtin_amdgcn_global_load_lds(
        (const __attribute__((address_space(1))) void*)g,
        (__attribute__((address_space(3))) void*)l,
        16, 0, 0);
}

// One-time W fp32 -> bf16 (32768 elems)
__global__ __launch_bounds__(256) void wconv_kernel(
    const float* __restrict__ W, ushort* __restrict__ Wbf)
{
    const int idx = (blockIdx.x * 256 + threadIdx.x) * 4;
    const float4 v = *(const float4*)(W + idx);
    ushort4 o;
    o.x = f2bf(v.x); o.y = f2bf(v.y); o.z = f2bf(v.z); o.w = f2bf(v.w);
    *(ushort4*)(Wbf + idx) = o;
}

// h[n][o] = relu(feats[n][:].W[o][:] + b[o]) via bf16 MFMA, h stored fp16.
// BARRIER-FREE per-wave pipeline: wave = 32 rows x all 128 cols, private
// 2x8KB LDS dbuf. Per chunk: issue breg(kc) [16 vmem] -> issue stage(kc+1)
// [8 gload_lds] -> s_waitcnt vmcnt(8) (chunk kc ready, kc+1 stays in flight)
// -> ds_read+cvt+MFMA. No __syncthreads -> no vmcnt(0) drain anywhere.
__global__ __launch_bounds__(256) void fc_mfma_kernel(
    const float* __restrict__ feats, const ushort* __restrict__ Wbf,
    const float* __restrict__ bias, __half* __restrict__ h, int N)
{
    __shared__ float lds_a[2 * MT * KC];   // 64 KB: per-wave 16 KB (2 bufs x 8 KB)
    char* lds = (char*)lds_a;

    const int tid  = threadIdx.x;
    const int lane = tid & 63;
    const int wv   = tid >> 6;
    const int l15  = lane & 15, lq = lane >> 4;
    const int nb   = blockIdx.x * MT;
    const int r0   = nb + wv * 32;         // wave's first global row
    char* wbase = lds + wv * 16384;        // this wave's private region

    // stage chunk kc into my buf: 8 x (1 KB DMA = 4 rows x 64 fp32).
    // source col pre-XOR-swizzled so linear LDS ends up swizzled (G4/m173).
    auto stage = [&](int kc, int buf) {
        #pragma unroll
        for (int it = 0; it < 8; ++it) {
            const int row = it * 4 + lq;               // local row 0..31
            const int c4  = l15 ^ (row & 7);
            int grow = r0 + row; if (grow > N - 1) grow = N - 1;
            const float* src = feats + (size_t)grow * DIN + kc * KC + c4 * 4;
            gload_lds16(src, wbase + buf * 8192 + it * 1024);
        }
    };

    f32x4 acc[2][8];
    #pragma unroll
    for (int mi = 0; mi < 2; ++mi)
        #pragma unroll
        for (int ni = 0; ni < 8; ++ni) acc[mi][ni] = (f32x4){0.f, 0.f, 0.f, 0.f};

    stage(0, 0);                                        // prologue: 8 in flight

    #pragma unroll
    for (int kc = 0; kc < DIN / KC; ++kc) {
        const int buf = kc & 1;

        // ---- 1) breg(kc): 16 vmem loads (L2-resident Wbf) ----
        bf16x8 breg[2][8];
        #pragma unroll
        for (int j = 0; j < 2; ++j)
            #pragma unroll
            for (int ni = 0; ni < 8; ++ni)
                breg[j][ni] = *(const bf16x8*)(
                    Wbf + (size_t)(ni * 16 + l15) * DIN + (kc * 2 + j) * 32 + lq * 8);
        __builtin_amdgcn_sched_barrier(0);   // pin: bregs issue before next stage

        // ---- 2) prefetch next chunk (stays in flight across compute) ----
        if (kc < DIN / KC - 1) stage(kc + 1, buf ^ 1);
        __builtin_amdgcn_sched_barrier(0);

        // ---- 3) wait: chunk kc DMA + bregs done; kc+1's 8 remain ----
        if (kc < DIN / KC - 1) asm volatile("s_waitcnt vmcnt(8)" ::: "memory");
        else                   asm volatile("s_waitcnt vmcnt(0)" ::: "memory");
        __builtin_amdgcn_sched_barrier(0);

        // ---- 4) compute: ds_read (swizzled) + cvt + 32 MFMA ----
        #pragma unroll
        for (int j = 0; j < 2; ++j) {
            bf16x8 a[2];
            #pragma unroll
            for (int mi = 0; mi < 2; ++mi) {
                const int row = mi * 16 + l15;          // local row 0..31
                const int X = (row & 7) << 4;
                const int b0 = buf * 8192 + row * 256 + j * 128 + lq * 32;
                const f32x4 lo = *(const f32x4*)(wbase + ((b0) ^ X));
                const f32x4 hi = *(const f32x4*)(wbase + ((b0 + 16) ^ X));
                uint4 u;
                u.x = cvtpk(lo.x, lo.y); u.y = cvtpk(lo.z, lo.w);
                u.z = cvtpk(hi.x, hi.y); u.w = cvtpk(hi.z, hi.w);
                union { uint4 q; bf16x8 v; } cv; cv.q = u;
                a[mi] = cv.v;
            }
            #pragma unroll
            for (int mi = 0; mi < 2; ++mi)
                #pragma unroll
                for (int ni = 0; ni < 8; ++ni)
                    acc[mi][ni] = __builtin_amdgcn_mfma_f32_16x16x32_bf16(
                        a[mi], breg[j][ni], acc[mi][ni], 0, 0, 0);
        }
    }

    // ---- epilogue: bias + relu -> fp16 h ----
    float bcol[8];
    #pragma unroll
    for (int ni = 0; ni < 8; ++ni) bcol[ni] = bias[ni * 16 + l15];

    #pragma unroll
    for (int mi = 0; mi < 2; ++mi) {
        const int rbase = r0 + mi * 16 + lq * 4;
        #pragma unroll
        for (int ni = 0; ni < 8; ++ni) {
            const int col = ni * 16 + l15;
            #pragma unroll
            for (int r = 0; r < 4; ++r) {
                const int n = rbase + r;
                if (n < N) {
                    const float v = fmaxf(acc[mi][ni][r] + bcol[ni], 0.f);
                    h[(size_t)n * DOUT + col] = __float2half_rn(v);
                }
            }
        }
    }
}

// pooled[n][:] = mean_k h[edge[n][k]][:]
// 16 nodes / 256-thr block, 16 lanes per node, 16 B (Half8) per lane.
// Best measured variant (45.7 us); sorted/paced/sliced all neutral-to-worse:
// random gather over 12.8 MB is L2-capacity/latency bound.
struct __align__(16) Half8 { __half2 a, b, c, d; };

__global__ __launch_bounds__(256) void pool_kernel(
    const __half* __restrict__ h, const int* __restrict__ edge,
    float* __restrict__ out, int N)
{
    __shared__ int eLds[16 * KNBR];            // 2 KB

    const int tid = threadIdx.x;
    const int g   = tid >> 4;                  // node group 0..15
    const int l   = tid & 15;
    const int nb  = blockIdx.x * 16;

    const int* esrc = edge + (size_t)nb * KNBR;
    eLds[tid]       = esrc[tid];
    eLds[tid + 256] = esrc[tid + 256];
    __syncthreads();

    const Half8* h8 = (const Half8*)h;         // row stride = DOUT/8 = 16
    const int* el = &eLds[g * KNBR];

    float4 acc0 = {0.f, 0.f, 0.f, 0.f};
    float4 acc1 = {0.f, 0.f, 0.f, 0.f};
    #pragma unroll
    for (int k = 0; k < KNBR; ++k) {
        const int idx = el[k];                 // uniform per 16-lane group
        const Half8 v = h8[(size_t)idx * (DOUT / 8) + l];
        const float2 f0 = __half22float2(v.a);
        const float2 f1 = __half22float2(v.b);
        const float2 f2 = __half22float2(v.c);
        const float2 f3 = __half22float2(v.d);
        acc0.x += f0.x; acc0.y += f0.y; acc0.z += f1.x; acc0.w += f1.y;
        acc1.x += f2.x; acc1.y += f2.y; acc1.z += f3.x; acc1.w += f3.y;
    }

    const float s = 1.0f / (float)KNBR;
    float4 r0, r1;
    r0.x = acc0.x * s; r0.y = acc0.y * s; r0.z = acc0.z * s; r0.w = acc0.w * s;
    r1.x = acc1.x * s; r1.y = acc1.y * s; r1.z = acc1.z * s; r1.w = acc1.w * s;

    const int node = nb + g;
    float4* op = (float4*)(out + (size_t)node * DOUT + l * 8);
    op[0] = r0; op[1] = r1;
}

extern "C" void kernel_launch(void* const* d_in, const int* in_sizes, int n_in,
                              void* d_out, int out_size, void* d_ws, size_t ws_size,
                              hipStream_t stream) {
    // dict order: ids, feats, W, b, edge_dict, G, ite
    const float* feats = (const float*)d_in[1];
    const float* W     = (const float*)d_in[2];
    const float* bias  = (const float*)d_in[3];
    const int*   edge  = (const int*)d_in[4];
    float* out = (float*)d_out;

    const int N = in_sizes[1] / DIN;            // 50000
    __half* h   = (__half*)d_ws;                // N*DOUT*2 = 12.8 MB
    ushort* Wbf = (ushort*)((char*)d_ws + (size_t)N * DOUT * sizeof(__half));

    wconv_kernel<<<(DOUT * DIN) / 1024, 256, 0, stream>>>(W, Wbf);
    fc_mfma_kernel<<<(N + MT - 1) / MT, 256, 0, stream>>>(feats, Wbf, bias, h, N);
    pool_kernel<<<N / 16, 256, 0, stream>>>(h, edge, out, N);
}